// Round 1
// baseline (461.559 us; speedup 1.0000x reference)
//
#include <hip/hip_runtime.h>

// Problem geometry (fixed by the reference).
#define NFRAMES 64
#define HH 1024
#define WW 1024
// quads per frame = H * (W/4) = 1024 * 256 = 2^18
#define QPF_SHIFT 18
#define QPF_MASK  ((1 << QPF_SHIFT) - 1)
#define W4_SHIFT  8   // W/4 = 256
#define W4_MASK   255

// JAX map_coordinates mode='mirror' index fixer: |((idx + s) mod 2s) - s|,
// s = size-1, applied to the INTEGER corner indices (floor(c) and floor(c)+1).
__device__ __forceinline__ int mirror_fix(int idx, int s, int m) {
    int t = (idx + s) % m;
    if (t < 0) t += m;
    t -= s;
    return t < 0 ? -t : t;
}

__global__ __launch_bounds__(256) void
flux_shift_kernel(const float* __restrict__ in,    // [N, H, W]
                  const float* __restrict__ flux,  // [N]
                  const float* __restrict__ noise, // [N]
                  const float* __restrict__ dydx,  // [N, 2]
                  float* __restrict__ out,         // [N, H, W]
                  int total_quads) {
    const int stride = gridDim.x * blockDim.x;
    for (int q = blockIdx.x * blockDim.x + threadIdx.x; q < total_quads; q += stride) {
        const int n   = q >> QPF_SHIFT;
        const int rem = q & QPF_MASK;
        const int y   = rem >> W4_SHIFT;
        const int x   = (rem & W4_MASK) << 2;

        // Frame-constant shift decomposition:
        //   coordinate = y - dy;  floor = y + floor(-dy);  frac = (-dy) - floor(-dy)
        const float dy = dydx[2 * n];
        const float dx = dydx[2 * n + 1];
        const float fl = flux[n];
        const float bi = noise[n];

        const float nky = floorf(-dy);
        const float nkx = floorf(-dx);
        const float fy = -dy - nky;          // in [0,1)
        const float fx = -dx - nkx;
        const int ky = (int)nky;
        const int kx = (int)nkx;

        const int ry0 = y + ky;              // lower row index (unfixed)
        const int cx0 = x + kx;              // lower col index of pixel 0 (unfixed)

        const float* __restrict__ base = in + (size_t)n * (HH * WW);
        const float gy = 1.0f - fy;
        const float gx = 1.0f - fx;

        float4 o;
        if ((unsigned)ry0 <= (unsigned)(HH - 2) && (unsigned)cx0 <= (unsigned)(WW - 5)) {
            // Interior fast path: rows ry0, ry0+1 and cols cx0..cx0+4 all in-bounds.
            const float* __restrict__ r0 = base + (size_t)ry0 * WW + cx0;
            const float* __restrict__ r1 = r0 + WW;
            const float a0 = r0[0], a1 = r0[1], a2 = r0[2], a3 = r0[3], a4 = r0[4];
            const float b0 = r1[0], b1 = r1[1], b2 = r1[2], b3 = r1[3], b4 = r1[4];
            // Vertical lerp (frame-constant fy), then horizontal lerp (fx).
            const float t0 = gy * a0 + fy * b0;
            const float t1 = gy * a1 + fy * b1;
            const float t2 = gy * a2 + fy * b2;
            const float t3 = gy * a3 + fy * b3;
            const float t4 = gy * a4 + fy * b4;
            o.x = (gx * t0 + fx * t1) * fl + bi;
            o.y = (gx * t1 + fx * t2) * fl + bi;
            o.z = (gx * t2 + fx * t3) * fl + bi;
            o.w = (gx * t3 + fx * t4) * fl + bi;
        } else {
            // Border path: full mirror fixing per corner index.
            const int sh = HH - 1, mh = 2 * sh;
            const int sw = WW - 1, mw = 2 * sw;
            const int iy0 = mirror_fix(ry0,     sh, mh);
            const int iy1 = mirror_fix(ry0 + 1, sh, mh);
            const float* __restrict__ r0 = base + (size_t)iy0 * WW;
            const float* __restrict__ r1 = base + (size_t)iy1 * WW;
            float res[4];
            #pragma unroll
            for (int j = 0; j < 4; ++j) {
                const int c0 = mirror_fix(cx0 + j,     sw, mw);
                const int c1 = mirror_fix(cx0 + j + 1, sw, mw);
                const float t0 = gy * r0[c0] + fy * r1[c0];
                const float t1 = gy * r0[c1] + fy * r1[c1];
                res[j] = (gx * t0 + fx * t1) * fl + bi;
            }
            o = make_float4(res[0], res[1], res[2], res[3]);
        }
        *reinterpret_cast<float4*>(out + (size_t)q * 4) = o;
    }
}

extern "C" void kernel_launch(void* const* d_in, const int* in_sizes, int n_in,
                              void* d_out, int out_size, void* d_ws, size_t ws_size,
                              hipStream_t stream) {
    const float* in    = (const float*)d_in[0]; // [1, N, H, W, 1]
    const float* flux  = (const float*)d_in[1]; // [N,1,1,1]
    const float* noise = (const float*)d_in[2]; // [N,1,1,1]
    const float* dydx  = (const float*)d_in[3]; // [N,2]
    float* out = (float*)d_out;

    const int total_quads = NFRAMES * HH * (WW / 4); // 16,777,216
    const int block = 256;
    const int grid  = 2048; // 8 blocks/CU on 256 CUs; grid-stride covers the rest

    flux_shift_kernel<<<grid, block, 0, stream>>>(in, flux, noise, dydx, out, total_quads);
}